// Round 2
// baseline (1368.091 us; speedup 1.0000x reference)
//
#include <hip/hip_runtime.h>
#include <hip/hip_bf16.h>
#include <math.h>

#define T_TOK 1024
#define H_DIM 1024
#define I_DIM 512
#define E_NUM 64
#define K_TOP 8
#define TM 128          // token rows per tile (expert segments padded to 128)
#define KT 64           // K-tile depth
#define APAD 72         // LDS row stride (bf16 elems): 144B rows, 2-way banks (free)
#define MAX_TILES 144   // sum ceil(n_e/128) <= 128, + 8 shared tiles
#define P_MAX 17408     // 16384 padded routed + 1024 shared

typedef __attribute__((ext_vector_type(8))) short short8;
typedef __attribute__((ext_vector_type(4))) float floatx4;

union F8 { short8 v; unsigned short h[8]; unsigned u[4]; };

__device__ __forceinline__ unsigned short f2bf(float f) {
  unsigned u = __builtin_bit_cast(unsigned, f);
  u += 0x7fffu + ((u >> 16) & 1u);   // RNE (no NaN inputs here)
  return (unsigned short)(u >> 16);
}

// ---------------- router: one wave per token, lane = expert ----------------
__global__ __launch_bounds__(64) void router_kernel(
    const float* __restrict__ x, const float* __restrict__ rw,
    int* __restrict__ topk_idx, float* __restrict__ topk_w, int* __restrict__ counts)
{
  int t = blockIdx.x;
  int lane = threadIdx.x;
  const float* xr = x + (size_t)t * H_DIM;
  float a0 = 0.f, a1 = 0.f, a2 = 0.f, a3 = 0.f;
  for (int h = 0; h < H_DIM; h += 4) {
    a0 = fmaf(xr[h + 0], rw[(size_t)(h + 0) * E_NUM + lane], a0);
    a1 = fmaf(xr[h + 1], rw[(size_t)(h + 1) * E_NUM + lane], a1);
    a2 = fmaf(xr[h + 2], rw[(size_t)(h + 2) * E_NUM + lane], a2);
    a3 = fmaf(xr[h + 3], rw[(size_t)(h + 3) * E_NUM + lane], a3);
  }
  float acc = (a0 + a1) + (a2 + a3);
  float aff = 1.f / (1.f + expf(-acc));   // sigmoid
  float v = aff;
  float vals[K_TOP]; int idxs[K_TOP];
  for (int k = 0; k < K_TOP; ++k) {
    float bv = v; int bi = lane;
    #pragma unroll
    for (int off = 32; off > 0; off >>= 1) {
      float ov = __shfl_down(bv, off);
      int   oi = __shfl_down(bi, off);
      if (ov > bv || (ov == bv && oi < bi)) { bv = ov; bi = oi; }  // jax tie: lower idx
    }
    bv = __shfl(bv, 0); bi = __shfl(bi, 0);
    vals[k] = bv; idxs[k] = bi;
    if (lane == bi) v = -1.f;
  }
  if (lane == 0) {
    float s = 0.f;
    for (int k = 0; k < K_TOP; ++k) s += vals[k];
    float inv = 1.f / (s + 1e-9f);
    for (int k = 0; k < K_TOP; ++k) {
      topk_idx[t * K_TOP + k] = idxs[k];
      topk_w[t * K_TOP + k] = vals[k] * inv;
      atomicAdd(&counts[idxs[k]], 1);
    }
  }
}

// ---------------- scan: padded offsets + tile table ----------------
__global__ void scan_tiles_kernel(int* counts, int* offsets, int* n_tiles,
                                  int* te, int* ts)
{
  if (threadIdx.x == 0 && blockIdx.x == 0) {
    counts[E_NUM] = T_TOK;  // shared expert gets every token
    int off = 0, nt = 0;
    for (int e = 0; e <= E_NUM; ++e) {
      offsets[e] = off;
      int c = counts[e];
      int tiles = (c + TM - 1) / TM;
      for (int i = 0; i < tiles; ++i) { te[nt] = e; ts[nt] = off + i * TM; ++nt; }
      off += tiles * TM;
    }
    *n_tiles = nt;
  }
}

// ---------------- fill grouped (token, weight) pair lists ----------------
__global__ __launch_bounds__(256) void fill_pairs_kernel(
    const int* __restrict__ topk_idx, const float* __restrict__ topk_w,
    const int* __restrict__ offsets, int* __restrict__ cursor,
    int* __restrict__ pair_token, float* __restrict__ pair_w)
{
  int tid = blockIdx.x * 256 + threadIdx.x;
  if (tid < T_TOK * K_TOP) {
    int t = tid >> 3;
    int e = topk_idx[tid];
    int pos = atomicAdd(&cursor[e], 1);
    int idx = offsets[e] + pos;
    pair_token[idx] = t;
    pair_w[idx] = topk_w[tid];
  } else if (tid < T_TOK * K_TOP + T_TOK) {
    int t = tid - T_TOK * K_TOP;
    int base = offsets[E_NUM];
    pair_token[base + t] = t;
    pair_w[base + t] = 1.0f;
  }
}

// ---------------- stage A: act = silu(x@Wg)*(x@Wu)*w  (bf16 MFMA) ----------------
// block: 256 thr (4 waves). tile: M=128 tokens x N=64 I-cols. wave w: n in [16w,16w+16).
__global__ __launch_bounds__(256) void stage_a_kernel(
    const float* __restrict__ x,
    const float* __restrict__ eg, const float* __restrict__ eu,
    const float* __restrict__ sg, const float* __restrict__ su,
    const int* __restrict__ te, const int* __restrict__ ts,
    const int* __restrict__ n_tiles,
    const int* __restrict__ pair_token, const float* __restrict__ pair_w,
    unsigned short* __restrict__ act)
{
  int tile = blockIdx.x;
  if (tile >= *n_tiles) return;
  int e = te[tile];
  int pstart = ts[tile];
  int i0 = blockIdx.y * 64;
  const float* Wg = (e < E_NUM) ? eg + (size_t)e * (H_DIM * I_DIM) : sg;
  const float* Wu = (e < E_NUM) ? eu + (size_t)e * (H_DIM * I_DIM) : su;

  __shared__ unsigned short As[TM][APAD];
  __shared__ int   tok_s[TM];
  __shared__ float w_s[TM];

  int tid = threadIdx.x;
  int lane = tid & 63;
  int wv = tid >> 6;
  if (tid < TM) {
    tok_s[tid] = pair_token[pstart + tid];
    w_s[tid]   = pair_w[pstart + tid];
  }
  __syncthreads();

  int sm = tid >> 4;          // staging row group 0..15
  int sk = (tid & 15) * 4;    // staging col 0..60
  int q  = lane >> 4;         // quad
  int ln = lane & 15;
  int nb = i0 + wv * 16;      // absolute I col base for this wave

  const float* xrow[8];
  #pragma unroll
  for (int i = 0; i < 8; ++i)
    xrow[i] = x + (size_t)tok_s[sm + 16 * i] * H_DIM + sk;

  const float* gbase = Wg + (size_t)(q * 8) * I_DIM + nb + ln;
  const float* ubase = Wu + (size_t)(q * 8) * I_DIM + nb + ln;

  floatx4 accg[8], accu[8];
  #pragma unroll
  for (int i = 0; i < 8; ++i) {
    accg[i] = (floatx4){0.f, 0.f, 0.f, 0.f};
    accu[i] = (floatx4){0.f, 0.f, 0.f, 0.f};
  }

  for (int k0 = 0; k0 < H_DIM; k0 += KT) {
    float4 xv[8];
    #pragma unroll
    for (int i = 0; i < 8; ++i)
      xv[i] = *(const float4*)(xrow[i] + k0);
    __syncthreads();
    #pragma unroll
    for (int i = 0; i < 8; ++i) {
      uint2 p;
      p.x = (unsigned)f2bf(xv[i].x) | ((unsigned)f2bf(xv[i].y) << 16);
      p.y = (unsigned)f2bf(xv[i].z) | ((unsigned)f2bf(xv[i].w) << 16);
      *(uint2*)&As[sm + 16 * i][sk] = p;
    }
    __syncthreads();

    #pragma unroll
    for (int kk = 0; kk < KT; kk += 32) {
      F8 bg, bu;
      const float* gp = gbase + (size_t)(k0 + kk) * I_DIM;
      const float* up = ubase + (size_t)(k0 + kk) * I_DIM;
      #pragma unroll
      for (int j = 0; j < 8; ++j) bg.h[j] = f2bf(gp[(size_t)j * I_DIM]);
      #pragma unroll
      for (int j = 0; j < 8; ++j) bu.h[j] = f2bf(up[(size_t)j * I_DIM]);
      #pragma unroll
      for (int i = 0; i < 8; ++i) {
        F8 af;
        uint2 lo = *(uint2*)&As[i * 16 + ln][kk + q * 8];
        uint2 hi = *(uint2*)&As[i * 16 + ln][kk + q * 8 + 4];
        af.u[0] = lo.x; af.u[1] = lo.y; af.u[2] = hi.x; af.u[3] = hi.y;
        accg[i] = __builtin_amdgcn_mfma_f32_16x16x32_bf16(af.v, bg.v, accg[i], 0, 0, 0);
        accu[i] = __builtin_amdgcn_mfma_f32_16x16x32_bf16(af.v, bu.v, accu[i], 0, 0, 0);
      }
    }
  }

  // epilogue: C[row = q*4+r + 16*mfrag][col = ln]
  #pragma unroll
  for (int i = 0; i < 8; ++i) {
    #pragma unroll
    for (int r = 0; r < 4; ++r) {
      int row = i * 16 + q * 4 + r;
      float g = accg[i][r];
      float u = accu[i][r];
      float sv = g / (1.f + __expf(-g));
      float o = sv * u * w_s[row];
      act[(size_t)(pstart + row) * I_DIM + nb + ln] = f2bf(o);
    }
  }
}

// ---------------- stage B: out[token] += act @ Wd  (bf16 MFMA) ----------------
// block: 256 thr (4 waves). tile: M=128 rows x N=64 H-cols.
__global__ __launch_bounds__(256) void stage_b_kernel(
    const unsigned short* __restrict__ act,
    const float* __restrict__ ed, const float* __restrict__ sd,
    const int* __restrict__ te, const int* __restrict__ ts,
    const int* __restrict__ n_tiles,
    const int* __restrict__ pair_token,
    float* __restrict__ out)
{
  int tile = blockIdx.x;
  if (tile >= *n_tiles) return;
  int e = te[tile];
  int pstart = ts[tile];
  int h0 = blockIdx.y * 64;
  const float* Wd = (e < E_NUM) ? ed + (size_t)e * (I_DIM * H_DIM) : sd;

  __shared__ unsigned short As[TM][APAD];
  __shared__ int tok_s[TM];

  int tid = threadIdx.x;
  int lane = tid & 63;
  int wv = tid >> 6;
  if (tid < TM) tok_s[tid] = pair_token[pstart + tid];
  __syncthreads();

  int srow = tid >> 3;        // 0..31
  int sc8  = (tid & 7) * 8;   // 0..56
  int q  = lane >> 4;
  int ln = lane & 15;
  int nb = h0 + wv * 16;

  const unsigned short* arow[4];
  #pragma unroll
  for (int i = 0; i < 4; ++i)
    arow[i] = act + (size_t)(pstart + srow + 32 * i) * I_DIM + sc8;

  const float* dbase = Wd + (size_t)(q * 8) * H_DIM + nb + ln;

  floatx4 acc[8];
  #pragma unroll
  for (int i = 0; i < 8; ++i) acc[i] = (floatx4){0.f, 0.f, 0.f, 0.f};

  for (int k0 = 0; k0 < I_DIM; k0 += KT) {
    uint4 av[4];
    #pragma unroll
    for (int i = 0; i < 4; ++i)
      av[i] = *(const uint4*)(arow[i] + k0);
    __syncthreads();
    #pragma unroll
    for (int i = 0; i < 4; ++i) {
      int m = srow + 32 * i;
      *(uint2*)&As[m][sc8]     = make_uint2(av[i].x, av[i].y);
      *(uint2*)&As[m][sc8 + 4] = make_uint2(av[i].z, av[i].w);
    }
    __syncthreads();

    #pragma unroll
    for (int kk = 0; kk < KT; kk += 32) {
      F8 bd;
      const float* dp = dbase + (size_t)(k0 + kk) * H_DIM;
      #pragma unroll
      for (int j = 0; j < 8; ++j) bd.h[j] = f2bf(dp[(size_t)j * H_DIM]);
      #pragma unroll
      for (int i = 0; i < 8; ++i) {
        F8 af;
        uint2 lo = *(uint2*)&As[i * 16 + ln][kk + q * 8];
        uint2 hi = *(uint2*)&As[i * 16 + ln][kk + q * 8 + 4];
        af.u[0] = lo.x; af.u[1] = lo.y; af.u[2] = hi.x; af.u[3] = hi.y;
        acc[i] = __builtin_amdgcn_mfma_f32_16x16x32_bf16(af.v, bd.v, acc[i], 0, 0, 0);
      }
    }
  }

  #pragma unroll
  for (int i = 0; i < 8; ++i) {
    #pragma unroll
    for (int r = 0; r < 4; ++r) {
      int row = i * 16 + q * 4 + r;
      int t = tok_s[row];
      atomicAdd(out + (size_t)t * H_DIM + nb + ln, acc[i][r]);
    }
  }
}

// ---------------- launch ----------------
extern "C" void kernel_launch(void* const* d_in, const int* in_sizes, int n_in,
                              void* d_out, int out_size, void* d_ws, size_t ws_size,
                              hipStream_t stream) {
  const float* x  = (const float*)d_in[0];
  const float* rw = (const float*)d_in[1];
  const float* sg = (const float*)d_in[2];
  const float* su = (const float*)d_in[3];
  const float* sd = (const float*)d_in[4];
  const float* eg = (const float*)d_in[5];
  const float* eu = (const float*)d_in[6];
  const float* ed = (const float*)d_in[7];
  float* out = (float*)d_out;

  int* counts   = (int*)d_ws;                    // 65
  int* offsets  = counts + 65;                   // 66
  int* cursor   = offsets + 66;                  // 65
  int* n_tiles  = cursor + 65;                   // 1   (first 197 ints zeroed)
  int* te       = n_tiles + 1;                   // 144
  int* ts       = te + MAX_TILES;                // 144
  int* topk_idx = ts + MAX_TILES;                // 8192
  int* pair_token = topk_idx + T_TOK * K_TOP;    // P_MAX
  float* topk_w = (float*)(pair_token + P_MAX);  // 8192
  float* pair_w = topk_w + T_TOK * K_TOP;        // P_MAX
  char* endp = (char*)(pair_w + P_MAX);
  size_t act_off = (((size_t)(endp - (char*)d_ws)) + 255) & ~(size_t)255;
  unsigned short* act = (unsigned short*)((char*)d_ws + act_off);  // P_MAX*512 bf16 ~17.8MB

  hipMemsetAsync(counts, 0, 197 * sizeof(int), stream);
  hipMemsetAsync(pair_token, 0, P_MAX * sizeof(int), stream);
  hipMemsetAsync(pair_w, 0, P_MAX * sizeof(float), stream);
  hipMemsetAsync(d_out, 0, (size_t)out_size * sizeof(float), stream);

  router_kernel<<<T_TOK, 64, 0, stream>>>(x, rw, topk_idx, topk_w, counts);
  scan_tiles_kernel<<<1, 64, 0, stream>>>(counts, offsets, n_tiles, te, ts);
  fill_pairs_kernel<<<(T_TOK * K_TOP + T_TOK + 255) / 256, 256, 0, stream>>>(
      topk_idx, topk_w, offsets, cursor, pair_token, pair_w);
  stage_a_kernel<<<dim3(MAX_TILES, I_DIM / 64), 256, 0, stream>>>(
      x, eg, eu, sg, su, te, ts, n_tiles, pair_token, pair_w, act);
  stage_b_kernel<<<dim3(MAX_TILES, H_DIM / 64), 256, 0, stream>>>(
      act, ed, sd, te, ts, n_tiles, pair_token, out);
}

// Round 3
// 676.463 us; speedup vs baseline: 2.0224x; 2.0224x over previous
//
#include <hip/hip_runtime.h>
#include <hip/hip_bf16.h>
#include <math.h>

#define T_TOK 1024
#define H_DIM 1024
#define I_DIM 512
#define E_NUM 64
#define K_TOP 8
#define TM 128          // token rows per tile (expert segments padded to 128)
#define KT 64           // K-tile depth
#define APAD 72         // LDS row stride (bf16 elems): 144B rows = 9x16B, b128-aligned
#define MAX_TILES 144   // sum ceil(n_e/128) <= 128 routed, + 8 shared
#define P_MAX 17408     // 16384 padded routed + 1024 shared

typedef __attribute__((ext_vector_type(8))) short short8;
typedef __attribute__((ext_vector_type(4))) float floatx4;

union F8 { short8 v; unsigned short h[8]; unsigned u[4]; uint4 q4; };

__device__ __forceinline__ unsigned short f2bf(float f) {
  unsigned u = __builtin_bit_cast(unsigned, f);
  u += 0x7fffu + ((u >> 16) & 1u);   // RNE (no NaN inputs here)
  return (unsigned short)(u >> 16);
}

// ---------------- router: one wave per token, lane = expert ----------------
__global__ __launch_bounds__(64) void router_kernel(
    const float* __restrict__ x, const float* __restrict__ rw,
    int* __restrict__ topk_idx, float* __restrict__ topk_w, int* __restrict__ counts)
{
  int t = blockIdx.x;
  int lane = threadIdx.x;
  const float* xr = x + (size_t)t * H_DIM;
  float a0 = 0.f, a1 = 0.f, a2 = 0.f, a3 = 0.f;
  for (int h = 0; h < H_DIM; h += 4) {
    a0 = fmaf(xr[h + 0], rw[(size_t)(h + 0) * E_NUM + lane], a0);
    a1 = fmaf(xr[h + 1], rw[(size_t)(h + 1) * E_NUM + lane], a1);
    a2 = fmaf(xr[h + 2], rw[(size_t)(h + 2) * E_NUM + lane], a2);
    a3 = fmaf(xr[h + 3], rw[(size_t)(h + 3) * E_NUM + lane], a3);
  }
  float acc = (a0 + a1) + (a2 + a3);
  float aff = 1.f / (1.f + expf(-acc));   // sigmoid
  float v = aff;
  float vals[K_TOP]; int idxs[K_TOP];
  for (int k = 0; k < K_TOP; ++k) {
    float bv = v; int bi = lane;
    #pragma unroll
    for (int off = 32; off > 0; off >>= 1) {
      float ov = __shfl_down(bv, off);
      int   oi = __shfl_down(bi, off);
      if (ov > bv || (ov == bv && oi < bi)) { bv = ov; bi = oi; }  // jax tie: lower idx
    }
    bv = __shfl(bv, 0); bi = __shfl(bi, 0);
    vals[k] = bv; idxs[k] = bi;
    if (lane == bi) v = -1.f;
  }
  if (lane == 0) {
    float s = 0.f;
    for (int k = 0; k < K_TOP; ++k) s += vals[k];
    float inv = 1.f / (s + 1e-9f);
    for (int k = 0; k < K_TOP; ++k) {
      topk_idx[t * K_TOP + k] = idxs[k];
      topk_w[t * K_TOP + k] = vals[k] * inv;
      atomicAdd(&counts[idxs[k]], 1);
    }
  }
}

// ---------------- scan: padded offsets + tile table ----------------
__global__ void scan_tiles_kernel(int* counts, int* offsets, int* n_tiles,
                                  int* te, int* ts)
{
  if (threadIdx.x == 0 && blockIdx.x == 0) {
    counts[E_NUM] = T_TOK;  // shared expert gets every token
    int off = 0, nt = 0;
    for (int e = 0; e <= E_NUM; ++e) {
      offsets[e] = off;
      int c = counts[e];
      int tiles = (c + TM - 1) / TM;
      for (int i = 0; i < tiles; ++i) { te[nt] = e; ts[nt] = off + i * TM; ++nt; }
      off += tiles * TM;
    }
    *n_tiles = nt;
  }
}

// ---------------- fill grouped (token, weight) pair lists ----------------
__global__ __launch_bounds__(256) void fill_pairs_kernel(
    const int* __restrict__ topk_idx, const float* __restrict__ topk_w,
    const int* __restrict__ offsets, int* __restrict__ cursor,
    int* __restrict__ pair_token, float* __restrict__ pair_w)
{
  int tid = blockIdx.x * 256 + threadIdx.x;
  if (tid < T_TOK * K_TOP) {
    int t = tid >> 3;
    int e = topk_idx[tid];
    int pos = atomicAdd(&cursor[e], 1);
    int idx = offsets[e] + pos;
    pair_token[idx] = t;
    pair_w[idx] = topk_w[tid];
  } else if (tid < T_TOK * K_TOP + T_TOK) {
    int t = tid - T_TOK * K_TOP;
    int base = offsets[E_NUM];
    pair_token[base + t] = t;
    pair_w[base + t] = 1.0f;
  }
}

// ---------------- stage A: act = silu(x@Wg)*(x@Wu)*w  (bf16 MFMA) ----------------
__global__ __launch_bounds__(256) void stage_a_kernel(
    const float* __restrict__ x,
    const float* __restrict__ eg, const float* __restrict__ eu,
    const float* __restrict__ sg, const float* __restrict__ su,
    const int* __restrict__ te, const int* __restrict__ ts,
    const int* __restrict__ n_tiles,
    const int* __restrict__ pair_token, const float* __restrict__ pair_w,
    unsigned short* __restrict__ act)
{
  int tile = blockIdx.x;
  if (tile >= *n_tiles) return;
  int e = te[tile];
  int pstart = ts[tile];
  int i0 = blockIdx.y * 64;
  const float* Wg = (e < E_NUM) ? eg + (size_t)e * (H_DIM * I_DIM) : sg;
  const float* Wu = (e < E_NUM) ? eu + (size_t)e * (H_DIM * I_DIM) : su;

  __shared__ unsigned short As[TM][APAD];
  __shared__ int   tok_s[TM];
  __shared__ float w_s[TM];

  int tid = threadIdx.x;
  int lane = tid & 63;
  int wv = tid >> 6;
  if (tid < TM) {
    tok_s[tid] = pair_token[pstart + tid];   // -1 for padding
    w_s[tid]   = pair_w[pstart + tid];       // 0 for padding
  }
  __syncthreads();

  int sm = tid >> 4;          // staging row group 0..15
  int sk = (tid & 15) * 4;    // staging col 0..60
  int q  = lane >> 4;         // quad
  int ln = lane & 15;
  int nb = i0 + wv * 16;      // absolute I col base for this wave

  const float* xrow[8];
  #pragma unroll
  for (int i = 0; i < 8; ++i) {
    int tk = tok_s[sm + 16 * i];
    if (tk < 0) tk = 0;       // padded: load token 0 (weight 0 -> zero act)
    xrow[i] = x + (size_t)tk * H_DIM + sk;
  }

  const float* gbase = Wg + (size_t)(q * 8) * I_DIM + nb + ln;
  const float* ubase = Wu + (size_t)(q * 8) * I_DIM + nb + ln;

  floatx4 accg[8], accu[8];
  #pragma unroll
  for (int i = 0; i < 8; ++i) {
    accg[i] = (floatx4){0.f, 0.f, 0.f, 0.f};
    accu[i] = (floatx4){0.f, 0.f, 0.f, 0.f};
  }

  for (int k0 = 0; k0 < H_DIM; k0 += KT) {
    float4 xv[8];
    #pragma unroll
    for (int i = 0; i < 8; ++i)
      xv[i] = *(const float4*)(xrow[i] + k0);
    __syncthreads();
    #pragma unroll
    for (int i = 0; i < 8; ++i) {
      uint2 p;
      p.x = (unsigned)f2bf(xv[i].x) | ((unsigned)f2bf(xv[i].y) << 16);
      p.y = (unsigned)f2bf(xv[i].z) | ((unsigned)f2bf(xv[i].w) << 16);
      *(uint2*)&As[sm + 16 * i][sk] = p;
    }
    __syncthreads();

    #pragma unroll
    for (int kk = 0; kk < KT; kk += 32) {
      F8 bg, bu;
      const float* gp = gbase + (size_t)(k0 + kk) * I_DIM;
      const float* up = ubase + (size_t)(k0 + kk) * I_DIM;
      #pragma unroll
      for (int j = 0; j < 8; ++j) bg.h[j] = f2bf(gp[(size_t)j * I_DIM]);
      #pragma unroll
      for (int j = 0; j < 8; ++j) bu.h[j] = f2bf(up[(size_t)j * I_DIM]);
      #pragma unroll
      for (int i = 0; i < 8; ++i) {
        F8 af;
        af.q4 = *(const uint4*)&As[i * 16 + ln][kk + q * 8];   // one ds_read_b128
        accg[i] = __builtin_amdgcn_mfma_f32_16x16x32_bf16(af.v, bg.v, accg[i], 0, 0, 0);
        accu[i] = __builtin_amdgcn_mfma_f32_16x16x32_bf16(af.v, bu.v, accu[i], 0, 0, 0);
      }
    }
  }

  // epilogue: C[row = q*4+r + 16*mfrag][col = ln]
  #pragma unroll
  for (int i = 0; i < 8; ++i) {
    #pragma unroll
    for (int r = 0; r < 4; ++r) {
      int row = i * 16 + q * 4 + r;
      float g = accg[i][r];
      float u = accu[i][r];
      float sv = g / (1.f + __expf(-g));
      float o = sv * u * w_s[row];
      act[(size_t)(pstart + row) * I_DIM + nb + ln] = f2bf(o);
    }
  }
}

// ---------------- stage B: out[token] += act @ Wd  (bf16 MFMA) ----------------
__global__ __launch_bounds__(256) void stage_b_kernel(
    const unsigned short* __restrict__ act,
    const float* __restrict__ ed, const float* __restrict__ sd,
    const int* __restrict__ te, const int* __restrict__ ts,
    const int* __restrict__ n_tiles,
    const int* __restrict__ pair_token,
    float* __restrict__ out)
{
  int tile = blockIdx.x;
  if (tile >= *n_tiles) return;
  int e = te[tile];
  int pstart = ts[tile];
  int h0 = blockIdx.y * 64;
  const float* Wd = (e < E_NUM) ? ed + (size_t)e * (I_DIM * H_DIM) : sd;

  __shared__ unsigned short As[TM][APAD];
  __shared__ int tok_s[TM];

  int tid = threadIdx.x;
  int lane = tid & 63;
  int wv = tid >> 6;
  if (tid < TM) tok_s[tid] = pair_token[pstart + tid];
  __syncthreads();

  int srow = tid >> 3;        // 0..31
  int sc8  = (tid & 7) * 8;   // 0..56
  int q  = lane >> 4;
  int ln = lane & 15;
  int nb = h0 + wv * 16;

  const unsigned short* arow[4];
  #pragma unroll
  for (int i = 0; i < 4; ++i)
    arow[i] = act + (size_t)(pstart + srow + 32 * i) * I_DIM + sc8;

  const float* dbase = Wd + (size_t)(q * 8) * H_DIM + nb + ln;

  floatx4 acc[8];
  #pragma unroll
  for (int i = 0; i < 8; ++i) acc[i] = (floatx4){0.f, 0.f, 0.f, 0.f};

  for (int k0 = 0; k0 < I_DIM; k0 += KT) {
    uint4 av[4];
    #pragma unroll
    for (int i = 0; i < 4; ++i)
      av[i] = *(const uint4*)(arow[i] + k0);
    __syncthreads();
    #pragma unroll
    for (int i = 0; i < 4; ++i) {
      int m = srow + 32 * i;
      *(uint2*)&As[m][sc8]     = make_uint2(av[i].x, av[i].y);
      *(uint2*)&As[m][sc8 + 4] = make_uint2(av[i].z, av[i].w);
    }
    __syncthreads();

    #pragma unroll
    for (int kk = 0; kk < KT; kk += 32) {
      F8 bd;
      const float* dp = dbase + (size_t)(k0 + kk) * H_DIM;
      #pragma unroll
      for (int j = 0; j < 8; ++j) bd.h[j] = f2bf(dp[(size_t)j * H_DIM]);
      #pragma unroll
      for (int i = 0; i < 8; ++i) {
        F8 af;
        af.q4 = *(const uint4*)&As[i * 16 + ln][kk + q * 8];   // one ds_read_b128
        acc[i] = __builtin_amdgcn_mfma_f32_16x16x32_bf16(af.v, bd.v, acc[i], 0, 0, 0);
      }
    }
  }

  #pragma unroll
  for (int i = 0; i < 8; ++i) {
    #pragma unroll
    for (int r = 0; r < 4; ++r) {
      int row = i * 16 + q * 4 + r;
      int t = tok_s[row];
      if (t >= 0)   // skip padded rows: avoids same-line atomic storm on token 0
        atomicAdd(out + (size_t)t * H_DIM + nb + ln, acc[i][r]);
    }
  }
}

// ---------------- launch ----------------
extern "C" void kernel_launch(void* const* d_in, const int* in_sizes, int n_in,
                              void* d_out, int out_size, void* d_ws, size_t ws_size,
                              hipStream_t stream) {
  const float* x  = (const float*)d_in[0];
  const float* rw = (const float*)d_in[1];
  const float* sg = (const float*)d_in[2];
  const float* su = (const float*)d_in[3];
  const float* sd = (const float*)d_in[4];
  const float* eg = (const float*)d_in[5];
  const float* eu = (const float*)d_in[6];
  const float* ed = (const float*)d_in[7];
  float* out = (float*)d_out;

  int* counts   = (int*)d_ws;                    // 65
  int* offsets  = counts + 65;                   // 66
  int* cursor   = offsets + 66;                  // 65
  int* n_tiles  = cursor + 65;                   // 1   (first 197 ints zeroed)
  int* te       = n_tiles + 1;                   // 144
  int* ts       = te + MAX_TILES;                // 144
  int* topk_idx = ts + MAX_TILES;                // 8192
  int* pair_token = topk_idx + T_TOK * K_TOP;    // P_MAX
  float* topk_w = (float*)(pair_token + P_MAX);  // 8192
  float* pair_w = topk_w + T_TOK * K_TOP;        // P_MAX
  char* endp = (char*)(pair_w + P_MAX);
  size_t act_off = (((size_t)(endp - (char*)d_ws)) + 255) & ~(size_t)255;
  unsigned short* act = (unsigned short*)((char*)d_ws + act_off);  // P_MAX*512 bf16 ~17.8MB

  hipMemsetAsync(counts, 0, 197 * sizeof(int), stream);
  hipMemsetAsync(pair_token, 0xFF, P_MAX * sizeof(int), stream);  // -1 sentinel
  hipMemsetAsync(pair_w, 0, P_MAX * sizeof(float), stream);
  hipMemsetAsync(d_out, 0, (size_t)out_size * sizeof(float), stream);

  router_kernel<<<T_TOK, 64, 0, stream>>>(x, rw, topk_idx, topk_w, counts);
  scan_tiles_kernel<<<1, 64, 0, stream>>>(counts, offsets, n_tiles, te, ts);
  fill_pairs_kernel<<<(T_TOK * K_TOP + T_TOK + 255) / 256, 256, 0, stream>>>(
      topk_idx, topk_w, offsets, cursor, pair_token, pair_w);
  stage_a_kernel<<<dim3(MAX_TILES, I_DIM / 64), 256, 0, stream>>>(
      x, eg, eu, sg, su, te, ts, n_tiles, pair_token, pair_w, act);
  stage_b_kernel<<<dim3(MAX_TILES, H_DIM / 64), 256, 0, stream>>>(
      act, ed, sd, te, ts, n_tiles, pair_token, out);
}